// Round 13
// baseline (274.955 us; speedup 1.0000x reference)
//
#include <hip/hip_runtime.h>
#include <math.h>

#define EPSV 1e-5f
#define MAXB 2176   // partial-stat slots (>= GBLK)
#define GBLK 2080   // gather grid (8 * 260)

typedef __attribute__((ext_vector_type(8))) short short8;   // 8 bf16 (4 VGPRs)
typedef __attribute__((ext_vector_type(4))) float f32x4;

__device__ __forceinline__ float gelu_f(float x) {
    return 0.5f * x * (1.0f + erff(x * 0.70710678118654752440f));
}

__device__ __forceinline__ float4 f4add(float4 a, float4 b) {
    return make_float4(a.x + b.x, a.y + b.y, a.z + b.z, a.w + b.w);
}

__device__ __forceinline__ ushort f2bf(float v) {
    union { float f; unsigned u; } a; a.f = v;
    unsigned r = a.u + 0x7FFFu + ((a.u >> 16) & 1u);  // RTNE
    return (ushort)(r >> 16);
}
__device__ __forceinline__ float bf2f(ushort h) {
    union { unsigned u; float f; } a; a.u = ((unsigned)h) << 16;
    return a.f;
}
__device__ __forceinline__ float4 bf4f(ushort4 v) {
    return make_float4(bf2f(v.x), bf2f(v.y), bf2f(v.z), bf2f(v.w));
}
// 8 fp32 -> bf16 hi/lo short8 pair
__device__ __forceinline__ void f8_to_bf(const float* f, short8& h, short8& l) {
    union { short8 v; ushort u[8]; } H, L;
#pragma unroll
    for (int j = 0; j < 8; ++j) {
        H.u[j] = f2bf(f[j]);
        L.u[j] = f2bf(f[j] - bf2f(H.u[j]));
    }
    h = H.v; l = L.v;
}

// ---------------- degree ----------------
__global__ void deg_kernel(const int* __restrict__ ei, int* __restrict__ deg, int E) {
    int stride = gridDim.x * blockDim.x;
    for (int e = blockIdx.x * blockDim.x + threadIdx.x; e < E; e += stride)
        atomicAdd(&deg[ei[E + e]], 1);
}

// ---------------- exclusive scan of deg -> off, fused dinv ----------------
__global__ __launch_bounds__(1024) void scan_kernel(const int* __restrict__ deg,
                                                    int* __restrict__ off,
                                                    float* __restrict__ dinv, int N) {
    __shared__ int sh[1024];
    int t = threadIdx.x;
    int chunk = (N + 1023) >> 10;
    int b = t * chunk;
    int e = b + chunk; if (e > N) e = N;
    int s = 0;
    for (int i = b; i < e; ++i) s += deg[i];
    sh[t] = s;
    __syncthreads();
    for (int d = 1; d < 1024; d <<= 1) {
        int v = (t >= d) ? sh[t - d] : 0;
        __syncthreads();
        sh[t] += v;
        __syncthreads();
    }
    int run = (t > 0) ? sh[t - 1] : 0;
    for (int i = b; i < e; ++i) {
        off[i] = run;
        run += deg[i];
        dinv[i] = rsqrtf((float)(deg[i] + 1));
    }
    if (t == 1023) off[N] = sh[1023];
}

// ---------------- CSR fill ----------------
__global__ void fill_kernel(const int* __restrict__ ei, const int* __restrict__ off,
                            int* __restrict__ fill, int* __restrict__ csr, int E) {
    int stride = gridDim.x * blockDim.x;
    for (int e = blockIdx.x * blockDim.x + threadIdx.x; e < E; e += stride) {
        int d = ei[E + e];
        int p = off[d] + atomicAdd(&fill[d], 1);
        csr[p] = ei[e];
    }
}

// ---------------- pack all 3 weights [K][F] fp32 -> Wt [F][K] bf16 hi/lo ----------------
__global__ void packw_all_kernel(const float* __restrict__ w0, const float* __restrict__ w1,
                                 const float* __restrict__ w2,
                                 ushort* __restrict__ wthi, ushort* __restrict__ wtlo)
{
    int idx = blockIdx.x * 256 + threadIdx.x;
    const float* W; int K, F, base, local;
    if (idx < 65536)       { W = w0; K = 256; F = 256; base = 0;     local = idx; }
    else if (idx < 98304)  { W = w1; K = 256; F = 128; base = 65536; local = idx - 65536; }
    else if (idx < 106496) { W = w2; K = 128; F = 64;  base = 98304; local = idx - 98304; }
    else return;
    int k = local / F, f = local - k * F;
    float v = W[local];
    ushort h = f2bf(v);
    wthi[base + f * K + k] = h;
    wtlo[base + f * K + k] = f2bf(v - bf2f(h));
}

// ---------------- LDS-staged split-bf16 MFMA GEMM, bf16 output ----------------
// hs[i][c] = bf16( dinv[i] * sum_k a[i][k] w[k][c] );  a=ahi+alo (split in-register),
// w=whi+wlo; 3 segments hi*hi + hi*lo + lo*hi. BM=128, BK=64, 4 waves (2x2).
// MODE 0: a = x (fp32, direct).  MODE 1: a = gelu(norm(t_bf16)) [+ res] (fused normgelu).
template<int K, int BN, int MODE>
__global__ __launch_bounds__(256) void gemm_mfma_kernel(
    const float* __restrict__ axf,          // MODE0: x
    const ushort* __restrict__ tsrc,        // MODE1: prev-layer t (bf16)
    const float* __restrict__ tm, const float* __restrict__ tis,
    const float* __restrict__ tgw, const float* __restrict__ tgb,
    const float* __restrict__ tga, const float* __restrict__ res,
    const ushort* __restrict__ wthi, const ushort* __restrict__ wtlo,
    const float* __restrict__ dinv, ushort* __restrict__ C,
    int M, int F)
{
    constexpr int BM = 128, BK = 64;
    constexpr int LDK = BK + 8;
    constexpr int CF  = BN / 32;
    constexpr int WCH = BN / 32;

    __shared__ ushort AsH[BM * LDK], AsL[BM * LDK];
    __shared__ ushort WsH[BN * LDK], WsL[BN * LDK];

    const int tid = threadIdx.x;
    const int l = tid & 63, w = tid >> 6;
    const int wr = w >> 1, wc = w & 1;
    const int m0   = blockIdx.y * BM;
    const int colB = blockIdx.x * BN;
    const int lr = l & 15, lkg = l >> 4;

    f32x4 acc[4][CF] = {};

    for (int kk = 0; kk < K; kk += BK) {
        short8 ra[4], rb[4], rwh[WCH], rwl[WCH];
#pragma unroll
        for (int i = 0; i < 4; ++i) {
            int q = tid + i * 256;
            int row = q >> 3, cc = q & 7;
            int rg = m0 + row; if (rg > M - 1) rg = M - 1;
            int kc = kk + cc * 8;
            float y[8];
            if constexpr (MODE == 0) {
                const float* xp = axf + (size_t)rg * K + kc;
                float4 v0 = *(const float4*)xp, v1 = *(const float4*)(xp + 4);
                y[0]=v0.x; y[1]=v0.y; y[2]=v0.z; y[3]=v0.w;
                y[4]=v1.x; y[5]=v1.y; y[6]=v1.z; y[7]=v1.w;
            } else {
                const ushort* tp = tsrc + (size_t)rg * K + kc;
                float4 v0 = bf4f(*(const ushort4*)tp);
                float4 v1 = bf4f(*(const ushort4*)(tp + 4));
                float4 m0v = *(const float4*)(tm + kc),  m1v = *(const float4*)(tm + kc + 4);
                float4 i0v = *(const float4*)(tis + kc), i1v = *(const float4*)(tis + kc + 4);
                float4 w0v = *(const float4*)(tgw + kc), w1v = *(const float4*)(tgw + kc + 4);
                float4 b0v = *(const float4*)(tgb + kc), b1v = *(const float4*)(tgb + kc + 4);
                float4 a0v = *(const float4*)(tga + kc), a1v = *(const float4*)(tga + kc + 4);
                y[0] = gelu_f(w0v.x * (v0.x - a0v.x * m0v.x) * i0v.x + b0v.x);
                y[1] = gelu_f(w0v.y * (v0.y - a0v.y * m0v.y) * i0v.y + b0v.y);
                y[2] = gelu_f(w0v.z * (v0.z - a0v.z * m0v.z) * i0v.z + b0v.z);
                y[3] = gelu_f(w0v.w * (v0.w - a0v.w * m0v.w) * i0v.w + b0v.w);
                y[4] = gelu_f(w1v.x * (v1.x - a1v.x * m1v.x) * i1v.x + b1v.x);
                y[5] = gelu_f(w1v.y * (v1.y - a1v.y * m1v.y) * i1v.y + b1v.y);
                y[6] = gelu_f(w1v.z * (v1.z - a1v.z * m1v.z) * i1v.z + b1v.z);
                y[7] = gelu_f(w1v.w * (v1.w - a1v.w * m1v.w) * i1v.w + b1v.w);
                if (res) {
                    const float* rp = res + (size_t)rg * K + kc;
                    float4 r0 = *(const float4*)rp, r1 = *(const float4*)(rp + 4);
                    y[0] += r0.x; y[1] += r0.y; y[2] += r0.z; y[3] += r0.w;
                    y[4] += r1.x; y[5] += r1.y; y[6] += r1.z; y[7] += r1.w;
                }
            }
            f8_to_bf(y, ra[i], rb[i]);
        }
#pragma unroll
        for (int i = 0; i < WCH; ++i) {
            int q = tid + i * 256;
            int row = q >> 3, cc = q & 7;
            rwh[i] = *(const short8*)(wthi + (size_t)(colB + row) * K + kk + cc * 8);
            rwl[i] = *(const short8*)(wtlo + (size_t)(colB + row) * K + kk + cc * 8);
        }
        __syncthreads();
#pragma unroll
        for (int i = 0; i < 4; ++i) {
            int q = tid + i * 256;
            int row = q >> 3, cc = q & 7;
            *(short8*)&AsH[row * LDK + cc * 8] = ra[i];
            *(short8*)&AsL[row * LDK + cc * 8] = rb[i];
        }
#pragma unroll
        for (int i = 0; i < WCH; ++i) {
            int q = tid + i * 256;
            int row = q >> 3, cc = q & 7;
            *(short8*)&WsH[row * LDK + cc * 8] = rwh[i];
            *(short8*)&WsL[row * LDK + cc * 8] = rwl[i];
        }
        __syncthreads();

#pragma unroll
        for (int ks = 0; ks < 2; ++ks) {
            const int kof = ks * 32 + lkg * 8;
            short8 afh[4], afl[4];
#pragma unroll
            for (int rf = 0; rf < 4; ++rf) {
                int row = wr * 64 + rf * 16 + lr;
                afh[rf] = *(const short8*)&AsH[row * LDK + kof];
                afl[rf] = *(const short8*)&AsL[row * LDK + kof];
            }
            short8 wfh[CF], wfl[CF];
#pragma unroll
            for (int cf = 0; cf < CF; ++cf) {
                int row = wc * (BN / 2) + cf * 16 + lr;
                wfh[cf] = *(const short8*)&WsH[row * LDK + kof];
                wfl[cf] = *(const short8*)&WsL[row * LDK + kof];
            }
#pragma unroll
            for (int rf = 0; rf < 4; ++rf) {
#pragma unroll
                for (int cf = 0; cf < CF; ++cf) {
                    acc[rf][cf] = __builtin_amdgcn_mfma_f32_16x16x32_bf16(afh[rf], wfh[cf], acc[rf][cf], 0, 0, 0);
                    acc[rf][cf] = __builtin_amdgcn_mfma_f32_16x16x32_bf16(afh[rf], wfl[cf], acc[rf][cf], 0, 0, 0);
                    acc[rf][cf] = __builtin_amdgcn_mfma_f32_16x16x32_bf16(afl[rf], wfh[cf], acc[rf][cf], 0, 0, 0);
                }
            }
        }
    }

#pragma unroll
    for (int rf = 0; rf < 4; ++rf) {
#pragma unroll
        for (int j = 0; j < 4; ++j) {
            int r = m0 + wr * 64 + rf * 16 + lkg * 4 + j;
            if (r < M) {
                float dv = dinv[r];
                ushort* Cp = C + (size_t)r * F + colB + wc * (BN / 2) + lr;
#pragma unroll
                for (int cf = 0; cf < CF; ++cf)
                    Cp[cf * 16] = f2bf(acc[rf][cf][j] * dv);
            }
        }
    }
}

// ---------------- column-sliced gather, bf16 hs input, bf16 t output ----------------
template<int F>
__global__ __launch_bounds__(256) void gather_kernel(
    const ushort* __restrict__ hs, const int* __restrict__ off,
    const int* __restrict__ csr, const float* __restrict__ dinv,
    const float* __restrict__ bias, ushort* __restrict__ t,
    float* __restrict__ p1, float* __restrict__ p2, int N)
{
    constexpr int NG  = F / 64;
    constexpr int NPB = 16;
    const int lane = threadIdx.x & 15;
    const int slot = threadIdx.x >> 4;

    const int xs    = blockIdx.x & 7;
    const int g     = xs % NG;
    const int r     = xs / NG;
    const int chunk = blockIdx.x >> 3;
    const int repl  = 8 / NG;
    const int nPerG = (int)(gridDim.x >> 3) * repl;
    const int j     = chunk * repl + r;

    const int col4 = g * 16 + lane;          // float4-column group
    const int c0 = col4 * 4;                 // first column
    const float4 bv = ((const float4*)bias)[col4];

    float4 a1 = make_float4(0.f, 0.f, 0.f, 0.f);
    float4 a2 = make_float4(0.f, 0.f, 0.f, 0.f);

    for (int d = j * NPB + slot; d < N; d += nPerG * NPB) {
        float4 acc = bf4f(*(const ushort4*)(hs + (size_t)d * F + c0));  // self loop
        const int e0 = off[d], e1 = off[d + 1];
        int e = e0;
        for (; e + 8 <= e1; e += 8) {
            int s0 = csr[e + 0], s1 = csr[e + 1], s2 = csr[e + 2], s3 = csr[e + 3];
            int s4 = csr[e + 4], s5 = csr[e + 5], s6 = csr[e + 6], s7 = csr[e + 7];
            ushort4 v0 = *(const ushort4*)(hs + (size_t)s0 * F + c0);
            ushort4 v1 = *(const ushort4*)(hs + (size_t)s1 * F + c0);
            ushort4 v2 = *(const ushort4*)(hs + (size_t)s2 * F + c0);
            ushort4 v3 = *(const ushort4*)(hs + (size_t)s3 * F + c0);
            ushort4 v4 = *(const ushort4*)(hs + (size_t)s4 * F + c0);
            ushort4 v5 = *(const ushort4*)(hs + (size_t)s5 * F + c0);
            ushort4 v6 = *(const ushort4*)(hs + (size_t)s6 * F + c0);
            ushort4 v7 = *(const ushort4*)(hs + (size_t)s7 * F + c0);
            float4 u0 = f4add(bf4f(v0), bf4f(v1));
            float4 u1 = f4add(bf4f(v2), bf4f(v3));
            float4 u2 = f4add(bf4f(v4), bf4f(v5));
            float4 u3 = f4add(bf4f(v6), bf4f(v7));
            acc = f4add(acc, f4add(f4add(u0, u1), f4add(u2, u3)));
        }
        for (; e + 2 <= e1; e += 2) {
            int s0 = csr[e + 0], s1 = csr[e + 1];
            ushort4 v0 = *(const ushort4*)(hs + (size_t)s0 * F + c0);
            ushort4 v1 = *(const ushort4*)(hs + (size_t)s1 * F + c0);
            acc = f4add(acc, f4add(bf4f(v0), bf4f(v1)));
        }
        if (e < e1) {
            acc = f4add(acc, bf4f(*(const ushort4*)(hs + (size_t)csr[e] * F + c0)));
        }

        float dv = dinv[d];
        float4 o;
        o.x = fmaf(dv, acc.x, bv.x);
        o.y = fmaf(dv, acc.y, bv.y);
        o.z = fmaf(dv, acc.z, bv.z);
        o.w = fmaf(dv, acc.w, bv.w);
        ushort4 ov;
        ov.x = f2bf(o.x); ov.y = f2bf(o.y); ov.z = f2bf(o.z); ov.w = f2bf(o.w);
        *(ushort4*)(t + (size_t)d * F + c0) = ov;
        a1.x += o.x; a1.y += o.y; a1.z += o.z; a1.w += o.w;
        a2.x += o.x * o.x; a2.y += o.y * o.y; a2.z += o.z * o.z; a2.w += o.w * o.w;
    }

    __shared__ float red[8][256];
    red[0][threadIdx.x] = a1.x; red[1][threadIdx.x] = a1.y;
    red[2][threadIdx.x] = a1.z; red[3][threadIdx.x] = a1.w;
    red[4][threadIdx.x] = a2.x; red[5][threadIdx.x] = a2.y;
    red[6][threadIdx.x] = a2.z; red[7][threadIdx.x] = a2.w;
    __syncthreads();
    if (slot == 0) {
        float sum[8];
#pragma unroll
        for (int k = 0; k < 8; ++k) {
            float s = red[k][lane];
            for (int jj = 1; jj < NPB; ++jj) s += red[k][jj * 16 + lane];
            sum[k] = s;
        }
        ((float4*)p1)[(long)col4 * MAXB + blockIdx.x] = make_float4(sum[0], sum[1], sum[2], sum[3]);
        ((float4*)p2)[(long)col4 * MAXB + blockIdx.x] = make_float4(sum[4], sum[5], sum[6], sum[7]);
    }
}

// ---------------- reduce partials -> meanv / istdv ----------------
__global__ __launch_bounds__(256) void statreduce_kernel(
    const float* __restrict__ p1, const float* __restrict__ p2,
    const float* __restrict__ ga,
    float* __restrict__ meanv, float* __restrict__ istdv,
    int nb, int N, int NG)
{
    const int c4 = blockIdx.x;
    const int g = (c4 >> 4) % NG;
    const float4* p14 = (const float4*)p1 + (long)c4 * MAXB;
    const float4* p24 = (const float4*)p2 + (long)c4 * MAXB;
    float4 a1 = make_float4(0.f, 0.f, 0.f, 0.f);
    float4 a2 = make_float4(0.f, 0.f, 0.f, 0.f);
    for (int r = threadIdx.x; r < nb; r += 256) {
        if (((r & 7) % NG) != g) continue;
        float4 v1 = p14[r];
        float4 v2 = p24[r];
        a1.x += v1.x; a1.y += v1.y; a1.z += v1.z; a1.w += v1.w;
        a2.x += v2.x; a2.y += v2.y; a2.z += v2.z; a2.w += v2.w;
    }
#pragma unroll
    for (int offv = 32; offv > 0; offv >>= 1) {
        a1.x += __shfl_down(a1.x, offv); a1.y += __shfl_down(a1.y, offv);
        a1.z += __shfl_down(a1.z, offv); a1.w += __shfl_down(a1.w, offv);
        a2.x += __shfl_down(a2.x, offv); a2.y += __shfl_down(a2.y, offv);
        a2.z += __shfl_down(a2.z, offv); a2.w += __shfl_down(a2.w, offv);
    }
    __shared__ float4 sh1[4], sh2[4];
    const int wid = threadIdx.x >> 6;
    if ((threadIdx.x & 63) == 0) { sh1[wid] = a1; sh2[wid] = a2; }
    __syncthreads();
    if (threadIdx.x == 0) {
        float4 t1 = sh1[0], t2 = sh2[0];
        for (int jj = 1; jj < 4; ++jj) {
            float4 u1 = sh1[jj], u2 = sh2[jj];
            t1.x += u1.x; t1.y += u1.y; t1.z += u1.z; t1.w += u1.w;
            t2.x += u2.x; t2.y += u2.y; t2.z += u2.z; t2.w += u2.w;
        }
        float s1a[4] = { t1.x, t1.y, t1.z, t1.w };
        float s2a[4] = { t2.x, t2.y, t2.z, t2.w };
#pragma unroll
        for (int k = 0; k < 4; ++k) {
            int c = c4 * 4 + k;
            float m = s1a[k] / (float)N;
            float a = ga[c];
            float var = s2a[k] / (float)N - 2.f * a * m * m + a * a * m * m;
            meanv[c] = m;
            istdv[c] = rsqrtf(var + EPSV);
        }
    }
}

// ---------------- pooling with fused graphnorm+gelu (fout = 64) ----------------
__device__ __forceinline__ void atomicMaxFloat(float* addr, float val) {
    unsigned* ua = (unsigned*)addr;
    unsigned old = *ua;
    while (true) {
        float of = __uint_as_float(old);
        if (of >= val) break;
        unsigned assumed = old;
        old = atomicCAS(ua, assumed, __float_as_uint(val));
        if (old == assumed) break;
    }
}

__global__ void initpool_kernel(float* __restrict__ psum, float* __restrict__ pmax) {
    int t = threadIdx.x;
    psum[t] = 0.f;
    pmax[t] = -INFINITY;
}

__global__ __launch_bounds__(256) void colpool_ng_kernel(
    const ushort* __restrict__ t, const float* __restrict__ meanv,
    const float* __restrict__ istdv, const float* __restrict__ gw,
    const float* __restrict__ gb, const float* __restrict__ ga,
    float* __restrict__ psum, float* __restrict__ pmax,
    int M, int rowsPerBlock)
{
    int c = threadIdx.x & 63;
    int rl = threadIdx.x >> 6;
    int r0 = blockIdx.x * rowsPerBlock;
    int rend = r0 + rowsPerBlock; if (rend > M) rend = M;
    const float mc = meanv[c], ic = istdv[c], wc_ = gw[c], bc_ = gb[c], ac = ga[c];
    float a1 = 0.f, am = -INFINITY;
    for (int r = r0 + rl; r < rend; r += 4) {
        float v = bf2f(t[(long)r * 64 + c]);
        float y = gelu_f(wc_ * (v - ac * mc) * ic + bc_);
        a1 += y; am = fmaxf(am, y);
    }
    __shared__ float sh1[256], shm[256];
    sh1[threadIdx.x] = a1; shm[threadIdx.x] = am;
    __syncthreads();
    if (threadIdx.x < 64) {
        for (int j = 1; j < 4; ++j) {
            a1 += sh1[c + j * 64];
            am = fmaxf(am, shm[c + j * 64]);
        }
        atomicAdd(&psum[c], a1);
        atomicMaxFloat(&pmax[c], am);
    }
}

// ---------------- head ----------------
__global__ void head_kernel(const float* __restrict__ psum, const float* __restrict__ pmax,
                            const float* __restrict__ wc1, const float* __restrict__ bc1,
                            const float* __restrict__ lnw, const float* __restrict__ lnb,
                            const float* __restrict__ wc2, const float* __restrict__ bc2,
                            float* __restrict__ out, int M)
{
    __shared__ float p[192];
    int t = threadIdx.x;
    float s = psum[t];
    p[t] = s / (float)M;
    p[64 + t] = pmax[t];
    p[128 + t] = s;
    __syncthreads();
    float h = bc1[t];
    for (int k = 0; k < 192; ++k) h = fmaf(p[k], wc1[k * 64 + t], h);
    float m = h;
    for (int off = 32; off > 0; off >>= 1) m += __shfl_xor(m, off);
    m *= (1.f / 64.f);
    float d = h - m;
    float v = d * d;
    for (int off = 32; off > 0; off >>= 1) v += __shfl_xor(v, off);
    v *= (1.f / 64.f);
    float y = d * rsqrtf(v + EPSV) * lnw[t] + lnb[t];
    y = gelu_f(y);
    float o0 = y * wc2[t * 2 + 0];
    float o1 = y * wc2[t * 2 + 1];
    for (int off = 32; off > 0; off >>= 1) {
        o0 += __shfl_xor(o0, off);
        o1 += __shfl_xor(o1, off);
    }
    if (t == 0) {
        out[0] = o0 + bc2[0];
        out[1] = o1 + bc2[1];
    }
}

extern "C" void kernel_launch(void* const* d_in, const int* in_sizes, int n_in,
                              void* d_out, int out_size, void* d_ws, size_t ws_size,
                              hipStream_t stream)
{
    const float* x    = (const float*)d_in[0];
    const int*   ei   = (const int*)d_in[1];
    const float* w0   = (const float*)d_in[2];
    const float* b0   = (const float*)d_in[3];
    const float* gn0w = (const float*)d_in[4];
    const float* gn0b = (const float*)d_in[5];
    const float* gn0a = (const float*)d_in[6];
    const float* w1   = (const float*)d_in[7];
    const float* b1   = (const float*)d_in[8];
    const float* gn1w = (const float*)d_in[9];
    const float* gn1b = (const float*)d_in[10];
    const float* gn1a = (const float*)d_in[11];
    const float* w2   = (const float*)d_in[12];
    const float* b2   = (const float*)d_in[13];
    const float* gn2w = (const float*)d_in[14];
    const float* gn2b = (const float*)d_in[15];
    const float* gn2a = (const float*)d_in[16];
    const float* wc1  = (const float*)d_in[17];
    const float* bc1  = (const float*)d_in[18];
    const float* lnw  = (const float*)d_in[19];
    const float* lnb  = (const float*)d_in[20];
    const float* wc2  = (const float*)d_in[21];
    const float* bc2  = (const float*)d_in[22];

    const int N = in_sizes[0] / 256;
    const int E = in_sizes[1] / 2;

    float* ws = (float*)d_ws;
    const size_t BIG = (size_t)N * 256;
    ushort* HS   = (ushort*)ws;             // hs (bf16, N x F)
    ushort* T    = (ushort*)(ws + BIG);     // t  (bf16, N x F)
    float* dinv  = ws + 2 * BIG;            // N floats
    int*   deg   = (int*)(dinv + N);        // N ints   } one memset covers
    int*   fill  = deg + N;                 // N ints   } deg+fill
    int*   off   = fill + N;                // N+1 ints
    int*   csr   = off + N + 1;             // E ints
    float* p1    = (float*)(csr + E);       // 64*MAXB float4
    float* p2    = p1 + (size_t)64 * MAXB * 4;
    float* meanv = p2 + (size_t)64 * MAXB * 4;   // 256
    float* istdv = meanv + 256;
    float* psum  = istdv + 256;             // 64
    float* pmax  = psum + 64;
    ushort* wthi = (ushort*)(pmax + 64);    // 106496 bf16 (all 3 layers)
    ushort* wtlo = wthi + 106496;
    const int woff[3] = { 0, 65536, 98304 };

    // CSR build (deg+fill zeroed in one memset; dinv fused into scan)
    hipMemsetAsync(deg, 0, (size_t)2 * N * sizeof(int), stream);
    deg_kernel<<<1024, 256, 0, stream>>>(ei, deg, E);
    scan_kernel<<<1, 1024, 0, stream>>>(deg, off, dinv, N);
    fill_kernel<<<1024, 256, 0, stream>>>(ei, off, fill, csr, E);
    packw_all_kernel<<<416, 256, 0, stream>>>(w0, w1, w2, wthi, wtlo);

    struct Layer {
        const float *b, *gw, *gb, *ga;
        int K, F;
    } L[3] = {
        { b0, gn0w, gn0b, gn0a, 256, 256 },
        { b1, gn1w, gn1b, gn1a, 256, 128 },
        { b2, gn2w, gn2b, gn2a, 128,  64 },
    };

    const int rowTiles = (N + 127) / 128;

    // ---- layer 0: A = x (fp32) ----
    gemm_mfma_kernel<256, 128, 0><<<dim3(2, rowTiles), 256, 0, stream>>>(
        x, nullptr, nullptr, nullptr, nullptr, nullptr, nullptr, nullptr,
        wthi + woff[0], wtlo + woff[0], dinv, HS, N, 256);
    gather_kernel<256><<<GBLK, 256, 0, stream>>>(HS, off, csr, dinv, L[0].b, T, p1, p2, N);
    statreduce_kernel<<<64, 256, 0, stream>>>(p1, p2, L[0].ga, meanv, istdv, GBLK, N, 4);

    // ---- layer 1: A = gelu(norm(t0)) + x  (fused in staging) ----
    gemm_mfma_kernel<256, 128, 1><<<dim3(1, rowTiles), 256, 0, stream>>>(
        nullptr, T, meanv, istdv, L[0].gw, L[0].gb, L[0].ga, x,
        wthi + woff[1], wtlo + woff[1], dinv, HS, N, 128);
    gather_kernel<128><<<GBLK, 256, 0, stream>>>(HS, off, csr, dinv, L[1].b, T, p1, p2, N);
    statreduce_kernel<<<32, 256, 0, stream>>>(p1, p2, L[1].ga, meanv, istdv, GBLK, N, 2);

    // ---- layer 2: A = gelu(norm(t1))  (fused in staging) ----
    gemm_mfma_kernel<128, 64, 1><<<dim3(1, rowTiles), 256, 0, stream>>>(
        nullptr, T, meanv, istdv, L[1].gw, L[1].gb, L[1].ga, nullptr,
        wthi + woff[2], wtlo + woff[2], dinv, HS, N, 64);
    gather_kernel<64><<<GBLK, 256, 0, stream>>>(HS, off, csr, dinv, L[2].b, T, p1, p2, N);
    statreduce_kernel<<<16, 256, 0, stream>>>(p1, p2, L[2].ga, meanv, istdv, GBLK, N, 1);

    // ---- pooling (fused gelu(norm(t2))) + head ----
    initpool_kernel<<<1, 64, 0, stream>>>(psum, pmax);
    colpool_ng_kernel<<<(N + 127) / 128, 256, 0, stream>>>(
        T, meanv, istdv, L[2].gw, L[2].gb, L[2].ga, psum, pmax, N, 128);
    head_kernel<<<1, 64, 0, stream>>>(psum, pmax, wc1, bc1, lnw, lnb, wc2, bc2,
                                      (float*)d_out, N);
}

// Round 14
// 267.215 us; speedup vs baseline: 1.0290x; 1.0290x over previous
//
#include <hip/hip_runtime.h>
#include <math.h>

#define EPSV 1e-5f
#define MAXB 2176   // partial-stat slots (>= GBLK)
#define GBLK 2080   // gather grid (8 * 260)

typedef __attribute__((ext_vector_type(8))) short short8;   // 8 bf16 (4 VGPRs)
typedef __attribute__((ext_vector_type(4))) float f32x4;

__device__ __forceinline__ float gelu_f(float x) {
    return 0.5f * x * (1.0f + erff(x * 0.70710678118654752440f));
}

__device__ __forceinline__ float4 f4add(float4 a, float4 b) {
    return make_float4(a.x + b.x, a.y + b.y, a.z + b.z, a.w + b.w);
}

__device__ __forceinline__ ushort f2bf(float v) {
    union { float f; unsigned u; } a; a.f = v;
    unsigned r = a.u + 0x7FFFu + ((a.u >> 16) & 1u);  // RTNE
    return (ushort)(r >> 16);
}
__device__ __forceinline__ float bf2f(ushort h) {
    union { unsigned u; float f; } a; a.u = ((unsigned)h) << 16;
    return a.f;
}
__device__ __forceinline__ float4 bf4f(ushort4 v) {
    return make_float4(bf2f(v.x), bf2f(v.y), bf2f(v.z), bf2f(v.w));
}
// 8 fp32 -> bf16 short8 (hi only)
__device__ __forceinline__ short8 f8_to_bf_hi(const float* f) {
    union { short8 v; ushort u[8]; } H;
#pragma unroll
    for (int j = 0; j < 8; ++j) H.u[j] = f2bf(f[j]);
    return H.v;
}

// ---------------- degree ----------------
__global__ void deg_kernel(const int* __restrict__ ei, int* __restrict__ deg, int E) {
    int stride = gridDim.x * blockDim.x;
    for (int e = blockIdx.x * blockDim.x + threadIdx.x; e < E; e += stride)
        atomicAdd(&deg[ei[E + e]], 1);
}

// ---------------- exclusive scan of deg -> off, fused dinv ----------------
__global__ __launch_bounds__(1024) void scan_kernel(const int* __restrict__ deg,
                                                    int* __restrict__ off,
                                                    float* __restrict__ dinv, int N) {
    __shared__ int sh[1024];
    int t = threadIdx.x;
    int chunk = (N + 1023) >> 10;
    int b = t * chunk;
    int e = b + chunk; if (e > N) e = N;
    int s = 0;
    for (int i = b; i < e; ++i) s += deg[i];
    sh[t] = s;
    __syncthreads();
    for (int d = 1; d < 1024; d <<= 1) {
        int v = (t >= d) ? sh[t - d] : 0;
        __syncthreads();
        sh[t] += v;
        __syncthreads();
    }
    int run = (t > 0) ? sh[t - 1] : 0;
    for (int i = b; i < e; ++i) {
        off[i] = run;
        run += deg[i];
        dinv[i] = rsqrtf((float)(deg[i] + 1));
    }
    if (t == 1023) off[N] = sh[1023];
}

// ---------------- CSR fill (blocks 0..1023)  ||  weight pack (blocks 1024..1439) ----------------
__global__ void fill_packw_kernel(const int* __restrict__ ei, const int* __restrict__ off,
                                  int* __restrict__ fill, int* __restrict__ csr, int E,
                                  const float* __restrict__ w0, const float* __restrict__ w1,
                                  const float* __restrict__ w2,
                                  ushort* __restrict__ wthi, ushort* __restrict__ wtlo)
{
    if (blockIdx.x < 1024) {
        int stride = 1024 * blockDim.x;
        for (int e = blockIdx.x * blockDim.x + threadIdx.x; e < E; e += stride) {
            int d = ei[E + e];
            int p = off[d] + atomicAdd(&fill[d], 1);
            csr[p] = ei[e];
        }
    } else {
        int idx = (blockIdx.x - 1024) * 256 + threadIdx.x;
        const float* W; int K, F, base, local;
        if (idx < 65536)       { W = w0; K = 256; F = 256; base = 0;     local = idx; }
        else if (idx < 98304)  { W = w1; K = 256; F = 128; base = 65536; local = idx - 65536; }
        else if (idx < 106496) { W = w2; K = 128; F = 64;  base = 98304; local = idx - 98304; }
        else return;
        int k = local / F, f = local - k * F;
        float v = W[local];
        ushort h = f2bf(v);
        wthi[base + f * K + k] = h;
        wtlo[base + f * K + k] = f2bf(v - bf2f(h));
    }
}

// ---------------- LDS-staged MFMA GEMM: A bf16, W split hi/lo (2 segments) ----------------
// hs[i][c] = bf16( dinv[i] * sum_k a[i][k] w[k][c] );  w = whi + wlo, a = bf16(a_src).
// BM=128, BK=64, 4 waves (2x2).
// MODE 0: a = x (fp32 -> bf16).  MODE 1: a = gelu(norm(t_bf16)) [+ res] (fused normgelu).
template<int K, int BN, int MODE>
__global__ __launch_bounds__(256) void gemm_mfma_kernel(
    const float* __restrict__ axf,          // MODE0: x
    const ushort* __restrict__ tsrc,        // MODE1: prev-layer t (bf16)
    const float* __restrict__ tm, const float* __restrict__ tis,
    const float* __restrict__ tgw, const float* __restrict__ tgb,
    const float* __restrict__ tga, const float* __restrict__ res,
    const ushort* __restrict__ wthi, const ushort* __restrict__ wtlo,
    const float* __restrict__ dinv, ushort* __restrict__ C,
    int M, int F)
{
    constexpr int BM = 128, BK = 64;
    constexpr int LDK = BK + 8;
    constexpr int CF  = BN / 32;
    constexpr int WCH = BN / 32;

    __shared__ ushort AsH[BM * LDK];
    __shared__ ushort WsH[BN * LDK], WsL[BN * LDK];

    const int tid = threadIdx.x;
    const int l = tid & 63, w = tid >> 6;
    const int wr = w >> 1, wc = w & 1;
    const int m0   = blockIdx.y * BM;
    const int colB = blockIdx.x * BN;
    const int lr = l & 15, lkg = l >> 4;

    f32x4 acc[4][CF] = {};

    for (int kk = 0; kk < K; kk += BK) {
        short8 ra[4], rwh[WCH], rwl[WCH];
#pragma unroll
        for (int i = 0; i < 4; ++i) {
            int q = tid + i * 256;
            int row = q >> 3, cc = q & 7;
            int rg = m0 + row; if (rg > M - 1) rg = M - 1;
            int kc = kk + cc * 8;
            float y[8];
            if constexpr (MODE == 0) {
                const float* xp = axf + (size_t)rg * K + kc;
                float4 v0 = *(const float4*)xp, v1 = *(const float4*)(xp + 4);
                y[0]=v0.x; y[1]=v0.y; y[2]=v0.z; y[3]=v0.w;
                y[4]=v1.x; y[5]=v1.y; y[6]=v1.z; y[7]=v1.w;
            } else {
                const ushort* tp = tsrc + (size_t)rg * K + kc;
                float4 v0 = bf4f(*(const ushort4*)tp);
                float4 v1 = bf4f(*(const ushort4*)(tp + 4));
                float4 m0v = *(const float4*)(tm + kc),  m1v = *(const float4*)(tm + kc + 4);
                float4 i0v = *(const float4*)(tis + kc), i1v = *(const float4*)(tis + kc + 4);
                float4 w0v = *(const float4*)(tgw + kc), w1v = *(const float4*)(tgw + kc + 4);
                float4 b0v = *(const float4*)(tgb + kc), b1v = *(const float4*)(tgb + kc + 4);
                float4 a0v = *(const float4*)(tga + kc), a1v = *(const float4*)(tga + kc + 4);
                y[0] = gelu_f(w0v.x * (v0.x - a0v.x * m0v.x) * i0v.x + b0v.x);
                y[1] = gelu_f(w0v.y * (v0.y - a0v.y * m0v.y) * i0v.y + b0v.y);
                y[2] = gelu_f(w0v.z * (v0.z - a0v.z * m0v.z) * i0v.z + b0v.z);
                y[3] = gelu_f(w0v.w * (v0.w - a0v.w * m0v.w) * i0v.w + b0v.w);
                y[4] = gelu_f(w1v.x * (v1.x - a1v.x * m1v.x) * i1v.x + b1v.x);
                y[5] = gelu_f(w1v.y * (v1.y - a1v.y * m1v.y) * i1v.y + b1v.y);
                y[6] = gelu_f(w1v.z * (v1.z - a1v.z * m1v.z) * i1v.z + b1v.z);
                y[7] = gelu_f(w1v.w * (v1.w - a1v.w * m1v.w) * i1v.w + b1v.w);
                if (res) {
                    const float* rp = res + (size_t)rg * K + kc;
                    float4 r0 = *(const float4*)rp, r1 = *(const float4*)(rp + 4);
                    y[0] += r0.x; y[1] += r0.y; y[2] += r0.z; y[3] += r0.w;
                    y[4] += r1.x; y[5] += r1.y; y[6] += r1.z; y[7] += r1.w;
                }
            }
            ra[i] = f8_to_bf_hi(y);
        }
#pragma unroll
        for (int i = 0; i < WCH; ++i) {
            int q = tid + i * 256;
            int row = q >> 3, cc = q & 7;
            rwh[i] = *(const short8*)(wthi + (size_t)(colB + row) * K + kk + cc * 8);
            rwl[i] = *(const short8*)(wtlo + (size_t)(colB + row) * K + kk + cc * 8);
        }
        __syncthreads();
#pragma unroll
        for (int i = 0; i < 4; ++i) {
            int q = tid + i * 256;
            int row = q >> 3, cc = q & 7;
            *(short8*)&AsH[row * LDK + cc * 8] = ra[i];
        }
#pragma unroll
        for (int i = 0; i < WCH; ++i) {
            int q = tid + i * 256;
            int row = q >> 3, cc = q & 7;
            *(short8*)&WsH[row * LDK + cc * 8] = rwh[i];
            *(short8*)&WsL[row * LDK + cc * 8] = rwl[i];
        }
        __syncthreads();

#pragma unroll
        for (int ks = 0; ks < 2; ++ks) {
            const int kof = ks * 32 + lkg * 8;
            short8 afh[4];
#pragma unroll
            for (int rf = 0; rf < 4; ++rf) {
                int row = wr * 64 + rf * 16 + lr;
                afh[rf] = *(const short8*)&AsH[row * LDK + kof];
            }
            short8 wfh[CF], wfl[CF];
#pragma unroll
            for (int cf = 0; cf < CF; ++cf) {
                int row = wc * (BN / 2) + cf * 16 + lr;
                wfh[cf] = *(const short8*)&WsH[row * LDK + kof];
                wfl[cf] = *(const short8*)&WsL[row * LDK + kof];
            }
#pragma unroll
            for (int rf = 0; rf < 4; ++rf) {
#pragma unroll
                for (int cf = 0; cf < CF; ++cf) {
                    acc[rf][cf] = __builtin_amdgcn_mfma_f32_16x16x32_bf16(afh[rf], wfh[cf], acc[rf][cf], 0, 0, 0);
                    acc[rf][cf] = __builtin_amdgcn_mfma_f32_16x16x32_bf16(afh[rf], wfl[cf], acc[rf][cf], 0, 0, 0);
                }
            }
        }
    }

#pragma unroll
    for (int rf = 0; rf < 4; ++rf) {
#pragma unroll
        for (int j = 0; j < 4; ++j) {
            int r = m0 + wr * 64 + rf * 16 + lkg * 4 + j;
            if (r < M) {
                float dv = dinv[r];
                ushort* Cp = C + (size_t)r * F + colB + wc * (BN / 2) + lr;
#pragma unroll
                for (int cf = 0; cf < CF; ++cf)
                    Cp[cf * 16] = f2bf(acc[rf][cf][j] * dv);
            }
        }
    }
}

// ---------------- column-sliced gather, bf16 hs input, bf16 t output ----------------
template<int F>
__global__ __launch_bounds__(256) void gather_kernel(
    const ushort* __restrict__ hs, const int* __restrict__ off,
    const int* __restrict__ csr, const float* __restrict__ dinv,
    const float* __restrict__ bias, ushort* __restrict__ t,
    float* __restrict__ p1, float* __restrict__ p2, int N)
{
    constexpr int NG  = F / 64;
    constexpr int NPB = 16;
    const int lane = threadIdx.x & 15;
    const int slot = threadIdx.x >> 4;

    const int xs    = blockIdx.x & 7;
    const int g     = xs % NG;
    const int r     = xs / NG;
    const int chunk = blockIdx.x >> 3;
    const int repl  = 8 / NG;
    const int nPerG = (int)(gridDim.x >> 3) * repl;
    const int j     = chunk * repl + r;

    const int col4 = g * 16 + lane;          // float4-column group
    const int c0 = col4 * 4;                 // first column
    const float4 bv = ((const float4*)bias)[col4];

    float4 a1 = make_float4(0.f, 0.f, 0.f, 0.f);
    float4 a2 = make_float4(0.f, 0.f, 0.f, 0.f);

    for (int d = j * NPB + slot; d < N; d += nPerG * NPB) {
        float4 acc = bf4f(*(const ushort4*)(hs + (size_t)d * F + c0));  // self loop
        const int e0 = off[d], e1 = off[d + 1];
        int e = e0;
        for (; e + 8 <= e1; e += 8) {
            int s0 = csr[e + 0], s1 = csr[e + 1], s2 = csr[e + 2], s3 = csr[e + 3];
            int s4 = csr[e + 4], s5 = csr[e + 5], s6 = csr[e + 6], s7 = csr[e + 7];
            ushort4 v0 = *(const ushort4*)(hs + (size_t)s0 * F + c0);
            ushort4 v1 = *(const ushort4*)(hs + (size_t)s1 * F + c0);
            ushort4 v2 = *(const ushort4*)(hs + (size_t)s2 * F + c0);
            ushort4 v3 = *(const ushort4*)(hs + (size_t)s3 * F + c0);
            ushort4 v4 = *(const ushort4*)(hs + (size_t)s4 * F + c0);
            ushort4 v5 = *(const ushort4*)(hs + (size_t)s5 * F + c0);
            ushort4 v6 = *(const ushort4*)(hs + (size_t)s6 * F + c0);
            ushort4 v7 = *(const ushort4*)(hs + (size_t)s7 * F + c0);
            float4 u0 = f4add(bf4f(v0), bf4f(v1));
            float4 u1 = f4add(bf4f(v2), bf4f(v3));
            float4 u2 = f4add(bf4f(v4), bf4f(v5));
            float4 u3 = f4add(bf4f(v6), bf4f(v7));
            acc = f4add(acc, f4add(f4add(u0, u1), f4add(u2, u3)));
        }
        for (; e + 2 <= e1; e += 2) {
            int s0 = csr[e + 0], s1 = csr[e + 1];
            ushort4 v0 = *(const ushort4*)(hs + (size_t)s0 * F + c0);
            ushort4 v1 = *(const ushort4*)(hs + (size_t)s1 * F + c0);
            acc = f4add(acc, f4add(bf4f(v0), bf4f(v1)));
        }
        if (e < e1) {
            acc = f4add(acc, bf4f(*(const ushort4*)(hs + (size_t)csr[e] * F + c0)));
        }

        float dv = dinv[d];
        float4 o;
        o.x = fmaf(dv, acc.x, bv.x);
        o.y = fmaf(dv, acc.y, bv.y);
        o.z = fmaf(dv, acc.z, bv.z);
        o.w = fmaf(dv, acc.w, bv.w);
        ushort4 ov;
        ov.x = f2bf(o.x); ov.y = f2bf(o.y); ov.z = f2bf(o.z); ov.w = f2bf(o.w);
        *(ushort4*)(t + (size_t)d * F + c0) = ov;
        a1.x += o.x; a1.y += o.y; a1.z += o.z; a1.w += o.w;
        a2.x += o.x * o.x; a2.y += o.y * o.y; a2.z += o.z * o.z; a2.w += o.w * o.w;
    }

    __shared__ float red[8][256];
    red[0][threadIdx.x] = a1.x; red[1][threadIdx.x] = a1.y;
    red[2][threadIdx.x] = a1.z; red[3][threadIdx.x] = a1.w;
    red[4][threadIdx.x] = a2.x; red[5][threadIdx.x] = a2.y;
    red[6][threadIdx.x] = a2.z; red[7][threadIdx.x] = a2.w;
    __syncthreads();
    if (slot == 0) {
        float sum[8];
#pragma unroll
        for (int k = 0; k < 8; ++k) {
            float s = red[k][lane];
            for (int jj = 1; jj < NPB; ++jj) s += red[k][jj * 16 + lane];
            sum[k] = s;
        }
        ((float4*)p1)[(long)col4 * MAXB + blockIdx.x] = make_float4(sum[0], sum[1], sum[2], sum[3]);
        ((float4*)p2)[(long)col4 * MAXB + blockIdx.x] = make_float4(sum[4], sum[5], sum[6], sum[7]);
    }
}

// ---------------- reduce partials -> meanv / istdv (optional extra init block) ----------------
__global__ __launch_bounds__(256) void statreduce_kernel(
    const float* __restrict__ p1, const float* __restrict__ p2,
    const float* __restrict__ ga,
    float* __restrict__ meanv, float* __restrict__ istdv,
    int nb, int N, int NG,
    float* __restrict__ psum, float* __restrict__ pmax)
{
    if (psum && blockIdx.x == gridDim.x - 1) {
        // init pooling accumulators (runs once, before colpool launch)
        if (threadIdx.x < 64) {
            psum[threadIdx.x] = 0.f;
            pmax[threadIdx.x] = -INFINITY;
        }
        return;
    }
    const int c4 = blockIdx.x;
    const int g = (c4 >> 4) % NG;
    const float4* p14 = (const float4*)p1 + (long)c4 * MAXB;
    const float4* p24 = (const float4*)p2 + (long)c4 * MAXB;
    float4 a1 = make_float4(0.f, 0.f, 0.f, 0.f);
    float4 a2 = make_float4(0.f, 0.f, 0.f, 0.f);
    for (int r = threadIdx.x; r < nb; r += 256) {
        if (((r & 7) % NG) != g) continue;
        float4 v1 = p14[r];
        float4 v2 = p24[r];
        a1.x += v1.x; a1.y += v1.y; a1.z += v1.z; a1.w += v1.w;
        a2.x += v2.x; a2.y += v2.y; a2.z += v2.z; a2.w += v2.w;
    }
#pragma unroll
    for (int offv = 32; offv > 0; offv >>= 1) {
        a1.x += __shfl_down(a1.x, offv); a1.y += __shfl_down(a1.y, offv);
        a1.z += __shfl_down(a1.z, offv); a1.w += __shfl_down(a1.w, offv);
        a2.x += __shfl_down(a2.x, offv); a2.y += __shfl_down(a2.y, offv);
        a2.z += __shfl_down(a2.z, offv); a2.w += __shfl_down(a2.w, offv);
    }
    __shared__ float4 sh1[4], sh2[4];
    const int wid = threadIdx.x >> 6;
    if ((threadIdx.x & 63) == 0) { sh1[wid] = a1; sh2[wid] = a2; }
    __syncthreads();
    if (threadIdx.x == 0) {
        float4 t1 = sh1[0], t2 = sh2[0];
        for (int jj = 1; jj < 4; ++jj) {
            float4 u1 = sh1[jj], u2 = sh2[jj];
            t1.x += u1.x; t1.y += u1.y; t1.z += u1.z; t1.w += u1.w;
            t2.x += u2.x; t2.y += u2.y; t2.z += u2.z; t2.w += u2.w;
        }
        float s1a[4] = { t1.x, t1.y, t1.z, t1.w };
        float s2a[4] = { t2.x, t2.y, t2.z, t2.w };
#pragma unroll
        for (int k = 0; k < 4; ++k) {
            int c = c4 * 4 + k;
            float m = s1a[k] / (float)N;
            float a = ga[c];
            float var = s2a[k] / (float)N - 2.f * a * m * m + a * a * m * m;
            meanv[c] = m;
            istdv[c] = rsqrtf(var + EPSV);
        }
    }
}

// ---------------- pooling with fused graphnorm+gelu (fout = 64) ----------------
__device__ __forceinline__ void atomicMaxFloat(float* addr, float val) {
    unsigned* ua = (unsigned*)addr;
    unsigned old = *ua;
    while (true) {
        float of = __uint_as_float(old);
        if (of >= val) break;
        unsigned assumed = old;
        old = atomicCAS(ua, assumed, __float_as_uint(val));
        if (old == assumed) break;
    }
}

__global__ __launch_bounds__(256) void colpool_ng_kernel(
    const ushort* __restrict__ t, const float* __restrict__ meanv,
    const float* __restrict__ istdv, const float* __restrict__ gw,
    const float* __restrict__ gb, const float* __restrict__ ga,
    float* __restrict__ psum, float* __restrict__ pmax,
    int M, int rowsPerBlock)
{
    int c = threadIdx.x & 63;
    int rl = threadIdx.x >> 6;
    int r0 = blockIdx.x * rowsPerBlock;
    int rend = r0 + rowsPerBlock; if (rend > M) rend = M;
    const float mc = meanv[c], ic = istdv[c], wc_ = gw[c], bc_ = gb[c], ac = ga[c];
    float a1 = 0.f, am = -INFINITY;
    for (int r = r0 + rl; r < rend; r += 4) {
        float v = bf2f(t[(long)r * 64 + c]);
        float y = gelu_f(wc_ * (v - ac * mc) * ic + bc_);
        a1 += y; am = fmaxf(am, y);
    }
    __shared__ float sh1[256], shm[256];
    sh1[threadIdx.x] = a1; shm[threadIdx.x] = am;
    __syncthreads();
    if (threadIdx.x < 64) {
        for (int j = 1; j < 4; ++j) {
            a1 += sh1[c + j * 64];
            am = fmaxf(am, shm[c + j * 64]);
        }
        atomicAdd(&psum[c], a1);
        atomicMaxFloat(&pmax[c], am);
    }
}

// ---------------- head ----------------
__global__ void head_kernel(const float* __restrict__ psum, const float* __restrict__ pmax,
                            const float* __restrict__ wc1, const float* __restrict__ bc1,
                            const float* __restrict__ lnw, const float* __restrict__ lnb,
                            const float* __restrict__ wc2, const float* __restrict__ bc2,
                            float* __restrict__ out, int M)
{
    __shared__ float p[192];
    int t = threadIdx.x;
    float s = psum[t];
    p[t] = s / (float)M;
    p[64 + t] = pmax[t];
    p[128 + t] = s;
    __syncthreads();
    float h = bc1[t];
    for (int k = 0; k < 192; ++k) h = fmaf(p[k], wc1[k * 64 + t], h);
    float m = h;
    for (int off = 32; off > 0; off >>= 1) m += __shfl_xor(m, off);
    m *= (1.f / 64.f);
    float d = h - m;
    float v = d * d;
    for (int off = 32; off > 0; off >>= 1) v += __shfl_xor(v, off);
    v *= (1.f / 64.f);
    float y = d * rsqrtf(v + EPSV) * lnw[t] + lnb[t];
    y = gelu_f(y);
    float o0 = y * wc2[t * 2 + 0];
    float o1 = y * wc2[t * 2 + 1];
    for (int off = 32; off > 0; off >>= 1) {
        o0 += __shfl_xor(o0, off);
        o1 += __shfl_xor(o1, off);
    }
    if (t == 0) {
        out[0] = o0 + bc2[0];
        out[1] = o1 + bc2[1];
    }
}

extern "C" void kernel_launch(void* const* d_in, const int* in_sizes, int n_in,
                              void* d_out, int out_size, void* d_ws, size_t ws_size,
                              hipStream_t stream)
{
    const float* x    = (const float*)d_in[0];
    const int*   ei   = (const int*)d_in[1];
    const float* w0   = (const float*)d_in[2];
    const float* b0   = (const float*)d_in[3];
    const float* gn0w = (const float*)d_in[4];
    const float* gn0b = (const float*)d_in[5];
    const float* gn0a = (const float*)d_in[6];
    const float* w1   = (const float*)d_in[7];
    const float* b1   = (const float*)d_in[8];
    const float* gn1w = (const float*)d_in[9];
    const float* gn1b = (const float*)d_in[10];
    const float* gn1a = (const float*)d_in[11];
    const float* w2   = (const float*)d_in[12];
    const float* b2   = (const float*)d_in[13];
    const float* gn2w = (const float*)d_in[14];
    const float* gn2b = (const float*)d_in[15];
    const float* gn2a = (const float*)d_in[16];
    const float* wc1  = (const float*)d_in[17];
    const float* bc1  = (const float*)d_in[18];
    const float* lnw  = (const float*)d_in[19];
    const float* lnb  = (const float*)d_in[20];
    const float* wc2  = (const float*)d_in[21];
    const float* bc2  = (const float*)d_in[22];

    const int N = in_sizes[0] / 256;
    const int E = in_sizes[1] / 2;

    float* ws = (float*)d_ws;
    const size_t BIG = (size_t)N * 256;
    ushort* HS   = (ushort*)ws;             // hs (bf16, N x F)
    ushort* T    = (ushort*)(ws + BIG);     // t  (bf16, N x F)
    float* dinv  = ws + 2 * BIG;            // N floats
    int*   deg   = (int*)(dinv + N);        // N ints   } one memset covers
    int*   fill  = deg + N;                 // N ints   } deg+fill
    int*   off   = fill + N;                // N+1 ints
    int*   csr   = off + N + 1;             // E ints
    float* p1    = (float*)(csr + E);       // 64*MAXB float4
    float* p2    = p1 + (size_t)64 * MAXB * 4;
    float* meanv = p2 + (size_t)64 * MAXB * 4;   // 256
    float* istdv = meanv + 256;
    float* psum  = istdv + 256;             // 64
    float* pmax  = psum + 64;
    ushort* wthi = (ushort*)(pmax + 64);    // 106496 bf16 (all 3 layers)
    ushort* wtlo = wthi + 106496;
    const int woff[3] = { 0, 65536, 98304 };

    // CSR build (deg+fill zeroed in one memset; dinv fused into scan; packw merged with fill)
    hipMemsetAsync(deg, 0, (size_t)2 * N * sizeof(int), stream);
    deg_kernel<<<1024, 256, 0, stream>>>(ei, deg, E);
    scan_kernel<<<1, 1024, 0, stream>>>(deg, off, dinv, N);
    fill_packw_kernel<<<1440, 256, 0, stream>>>(ei, off, fill, csr, E, w0, w1, w2, wthi, wtlo);

    struct Layer {
        const float *b, *gw, *gb, *ga;
        int K, F;
    } L[3] = {
        { b0, gn0w, gn0b, gn0a, 256, 256 },
        { b1, gn1w, gn1b, gn1a, 256, 128 },
        { b2, gn2w, gn2b, gn2a, 128,  64 },
    };

    const int rowTiles = (N + 127) / 128;

    // ---- layer 0: A = x (fp32 -> bf16) ----
    gemm_mfma_kernel<256, 128, 0><<<dim3(2, rowTiles), 256, 0, stream>>>(
        x, nullptr, nullptr, nullptr, nullptr, nullptr, nullptr, nullptr,
        wthi + woff[0], wtlo + woff[0], dinv, HS, N, 256);
    gather_kernel<256><<<GBLK, 256, 0, stream>>>(HS, off, csr, dinv, L[0].b, T, p1, p2, N);
    statreduce_kernel<<<64, 256, 0, stream>>>(p1, p2, L[0].ga, meanv, istdv, GBLK, N, 4,
                                              nullptr, nullptr);

    // ---- layer 1: A = gelu(norm(t0)) + x  (fused in staging) ----
    gemm_mfma_kernel<256, 128, 1><<<dim3(1, rowTiles), 256, 0, stream>>>(
        nullptr, T, meanv, istdv, L[0].gw, L[0].gb, L[0].ga, x,
        wthi + woff[1], wtlo + woff[1], dinv, HS, N, 128);
    gather_kernel<128><<<GBLK, 256, 0, stream>>>(HS, off, csr, dinv, L[1].b, T, p1, p2, N);
    statreduce_kernel<<<32, 256, 0, stream>>>(p1, p2, L[1].ga, meanv, istdv, GBLK, N, 2,
                                              nullptr, nullptr);

    // ---- layer 2: A = gelu(norm(t1))  (fused in staging) ----
    gemm_mfma_kernel<128, 64, 1><<<dim3(1, rowTiles), 256, 0, stream>>>(
        nullptr, T, meanv, istdv, L[1].gw, L[1].gb, L[1].ga, nullptr,
        wthi + woff[2], wtlo + woff[2], dinv, HS, N, 64);
    gather_kernel<64><<<GBLK, 256, 0, stream>>>(HS, off, csr, dinv, L[2].b, T, p1, p2, N);
    statreduce_kernel<<<17, 256, 0, stream>>>(p1, p2, L[2].ga, meanv, istdv, GBLK, N, 1,
                                              psum, pmax);   // extra block inits pooling

    // ---- pooling (fused gelu(norm(t2))) + head ----
    colpool_ng_kernel<<<(N + 127) / 128, 256, 0, stream>>>(
        T, meanv, istdv, L[2].gw, L[2].gb, L[2].ga, psum, pmax, N, 128);
    head_kernel<<<1, 64, 0, stream>>>(psum, pmax, wc1, bc1, lnw, lnb, wc2, bc2,
                                      (float*)d_out, N);
}